// Round 3
// baseline (5494.617 us; speedup 1.0000x reference)
//
#include <hip/hip_runtime.h>
#include <cstdint>
#include <cstddef>

// Problem constants
static constexpr int Bn  = 32;     // batch
static constexpr int Tn  = 32;     // decoder steps
static constexpr int Sn  = 100;    // encoder length
static constexpr int Vn  = 20000;  // vocab
static constexpr int SEn = 400;    // word emb
static constexpr int EINn= 460;    // SE + FR
static constexpr int Hn  = 512;    // decoder hidden
static constexpr int HHn = 256;    // per-direction encoder hidden
static constexpr int TEn = 300;    // target emb

__device__ __forceinline__ float sigm(float x) { return 1.f / (1.f + expf(-x)); }

__device__ __forceinline__ void fma4(float hk, const float4 w,
                                     float& zi, float& zf, float& zg, float& zo) {
    zi = fmaf(hk, w.x, zi); zf = fmaf(hk, w.y, zf);
    zg = fmaf(hk, w.z, zg); zo = fmaf(hk, w.w, zo);
}

__device__ __forceinline__ void grid_wait(int* bar, int target) {
    while (__hip_atomic_load(bar, __ATOMIC_ACQUIRE, __HIP_MEMORY_SCOPE_AGENT) < target)
        __builtin_amdgcn_s_sleep(2);
}

// ---------------------------------------------------------------------------
// Embedding gathers
// ---------------------------------------------------------------------------
__global__ __launch_bounds__(256) void embed_kernel(
    const int* __restrict__ value, const int* __restrict__ field,
    const int* __restrict__ ppos, const int* __restrict__ pneg,
    const int* __restrict__ sent,
    const float* __restrict__ sent_emb, const float* __restrict__ field_emb,
    const float* __restrict__ ppos_emb, const float* __restrict__ pneg_emb,
    float* __restrict__ enc_in, float* __restrict__ x_seq)
{
    int i = blockIdx.x * 256 + threadIdx.x;
    const int total1 = Bn * Sn * EINn;
    if (i < total1) {
        int e = i % EINn, bs = i / EINn;
        float v;
        if (e < SEn)      v = sent_emb[(size_t)value[bs] * SEn + e];
        else if (e < 450) v = field_emb[field[bs] * 50 + (e - 400)];
        else if (e < 455) v = ppos_emb[ppos[bs] * 5 + (e - 450)];
        else              v = pneg_emb[pneg[bs] * 5 + (e - 455)];
        enc_in[i] = v;
    } else {
        int i2 = i - total1;
        if (i2 < Bn * Tn * SEn) {
            int e = i2 % SEn, bt = i2 / SEn;
            x_seq[i2] = sent_emb[(size_t)sent[bt] * SEn + e];
        }
    }
}

// ---------------------------------------------------------------------------
// Weight transposes into [k][u][gate] float4 layout for the LSTM kernels.
// enc: Wh[k][g*256+u] -> Wt[(k*256+u)*4+g], k,u in [0,256)
// dec: Wh[k][g*512+u] -> Wt[(k*512+u)*4+g], k,u in [0,512)
// ---------------------------------------------------------------------------
__global__ __launch_bounds__(256) void transpose_wh_kernel(
    const float* __restrict__ Whf, const float* __restrict__ Whb,
    const float* __restrict__ Whd,
    float* __restrict__ Whf_t, float* __restrict__ Whb_t, float* __restrict__ Whd_t)
{
    int i = blockIdx.x * 256 + threadIdx.x;
    if (i < 65536) {  // 256*256
        int k = i >> 8, u = i & 255;
        const float* p = Whf + (size_t)k * 1024 + u;
        float4 o;
        o.x = p[0]; o.y = p[256]; o.z = p[512]; o.w = p[768];
        *(float4*)(Whf_t + (size_t)i * 4) = o;
        p = Whb + (size_t)k * 1024 + u;
        o.x = p[0]; o.y = p[256]; o.z = p[512]; o.w = p[768];
        *(float4*)(Whb_t + (size_t)i * 4) = o;
    } else {
        int j = i - 65536;  // 512*512 entries
        if (j < 262144) {
            int k = j >> 9, u = j & 511;
            const float* p = Whd + (size_t)k * 2048 + u;
            float4 o;
            o.x = p[0]; o.y = p[512]; o.z = p[1024]; o.w = p[1536];
            *(float4*)(Whd_t + (size_t)j * 4) = o;
        }
    }
}

// ---------------------------------------------------------------------------
// Generic fp32 tiled GEMM (unchanged)
// ---------------------------------------------------------------------------
__global__ __launch_bounds__(256) void gemm128_kernel(
    const float* __restrict__ A, const float* __restrict__ Bm,
    const float* __restrict__ bias, float* __restrict__ C,
    int M, int N, int K, int lda, int ldb, int ldc)
{
    __shared__ float As[8][128];
    __shared__ float Bs[8][128];
    const int bm = blockIdx.y * 128, bn = blockIdx.x * 128;
    const int tid = threadIdx.x;
    const int tx = tid & 15, ty = tid >> 4;
    const int row0 = ty * 8, col0 = tx * 8;
    float acc[8][8] = {};
    for (int k0 = 0; k0 < K; k0 += 8) {
        #pragma unroll
        for (int i = 0; i < 4; ++i) {
            int idx = tid + 256 * i;
            int m = idx >> 3, kk = idx & 7;
            float v = 0.f;
            if (bm + m < M && k0 + kk < K) v = A[(size_t)(bm + m) * lda + (k0 + kk)];
            As[kk][m] = v;
        }
        #pragma unroll
        for (int i = 0; i < 4; ++i) {
            int idx = tid + 256 * i;
            int kk = idx >> 7, n = idx & 127;
            float v = 0.f;
            if (k0 + kk < K && bn + n < N) v = Bm[(size_t)(k0 + kk) * ldb + (bn + n)];
            Bs[kk][n] = v;
        }
        __syncthreads();
        #pragma unroll
        for (int kk = 0; kk < 8; ++kk) {
            float a[8], b[8];
            #pragma unroll
            for (int i = 0; i < 8; ++i) a[i] = As[kk][row0 + i];
            #pragma unroll
            for (int j = 0; j < 8; ++j) b[j] = Bs[kk][col0 + j];
            #pragma unroll
            for (int i = 0; i < 8; ++i)
                #pragma unroll
                for (int j = 0; j < 8; ++j) acc[i][j] = fmaf(a[i], b[j], acc[i][j]);
        }
        __syncthreads();
    }
    #pragma unroll
    for (int i = 0; i < 8; ++i) {
        int m = bm + row0 + i;
        if (m >= M) continue;
        #pragma unroll
        for (int j = 0; j < 8; ++j) {
            int n = bn + col0 + j;
            if (n < N) {
                float v = acc[i][j];
                if (bias) v += bias[n];
                C[(size_t)m * ldc + n] = v;
            }
        }
    }
}

// ---------------------------------------------------------------------------
// Encoder bidir LSTM v4 — batch-reuse, BIT-EXACT round-0 arithmetic.
// 64 blocks: block bb -> dir = bb>>5, units [(bb&31)*8, +8) of that dir.
// Thread: b = tid&31 (batch), uu = tid>>5 -> unit = U0+uu.
// Each thread computes its (b,unit) gates with the full K=256 sequential
// fmaf chain, x-first, k-ascending — identical op order to the proven
// round-0 kernel, so all outputs are bit-identical. Weights broadcast
// across the 32 batch lanes (read once per step per block).
// h exchange: [k][b]-transposed double-buffered agent-scope buffer +
// monotonic atomic-counter grid barrier.
// ---------------------------------------------------------------------------
__global__ __launch_bounds__(256, 1) void enc_lstm4_kernel(
    const float* __restrict__ Xf, const float* __restrict__ Xb,
    const float4* __restrict__ Whf_t, const float4* __restrict__ Whb_t,
    float* __restrict__ enc_out, float* __restrict__ h0t, float* __restrict__ c0t,
    float* __restrict__ hbuf, int* __restrict__ bar)
{
    const int bb  = blockIdx.x;
    const int dir = bb >> 5;
    const int U0  = (bb & 31) * 8;
    const float*  __restrict__ X = dir ? Xb : Xf;
    const float4* __restrict__ W = dir ? Whb_t : Whf_t;
    float* hb = hbuf + dir * 16384;          // per dir: [2][256*32], [k][b] layout
    const int tid = threadIdx.x;
    const int b = tid & 31, uu = tid >> 5;
    const int unit = U0 + uu;
    const float4* __restrict__ wcol = W + unit;   // stride 256 float4 per k
    float c = 0.f;

    for (int s = 0; s < Sn; ++s) {
        const int src_s = dir ? (Sn - 1 - s) : s;
        const float* xr = X + ((size_t)(b * Sn + src_s)) * 1024 + unit;
        float zi = xr[0], zf = xr[256], zg = xr[512], zo = xr[768];
        if (s > 0) {
            if (tid == 0) grid_wait(bar, 64 * s);
            __syncthreads();
            const float* hsrc = hb + ((s - 1) & 1) * 8192 + b;
            #pragma unroll 8
            for (int k = 0; k < 256; ++k) {
                const float hv = __hip_atomic_load(&hsrc[k * 32],
                                   __ATOMIC_RELAXED, __HIP_MEMORY_SCOPE_AGENT);
                fma4(hv, wcol[(size_t)k * 256], zi, zf, zg, zo);
            }
        }
        c = sigm(zf) * c + sigm(zi) * tanhf(zg);
        const float h = sigm(zo) * tanhf(c);
        enc_out[((size_t)(b * Sn + src_s)) * Hn + dir * HHn + unit] = h;
        if (s == Sn - 1) {
            h0t[(dir * HHn + unit) * 32 + b] = h;   // [k][b] transposed
            c0t[(dir * HHn + unit) * 32 + b] = c;
        } else {
            __hip_atomic_store(&hb[(s & 1) * 8192 + unit * 32 + b], h,
                               __ATOMIC_RELEASE, __HIP_MEMORY_SCOPE_AGENT);
            __syncthreads();
            if (tid == 0)
                __hip_atomic_fetch_add(bar, 1, __ATOMIC_ACQ_REL, __HIP_MEMORY_SCOPE_AGENT);
        }
    }
}

// ---------------------------------------------------------------------------
// Decoder LSTM v4 — batch-reuse, BIT-EXACT round-0 arithmetic.
// 64 blocks: block bb owns units [bb*8, +8) for ALL 32 batches.
// Thread: b = tid&31, uu = tid>>5 -> unit = U0+uu; full K=512 sequential
// fmaf chain, x-first, k-ascending (round-0 op order, bit-identical).
// Weight traffic: 4 MB/step grid-wide (was 128 MB in the 4200 µs baseline).
// ---------------------------------------------------------------------------
__global__ __launch_bounds__(256, 1) void dec_lstm4_kernel(
    const float* __restrict__ Xd, const float4* __restrict__ Whd_t,
    const float* __restrict__ h0t, const float* __restrict__ c0t,
    float* __restrict__ h_all, float* __restrict__ hT, float* __restrict__ cT,
    float* __restrict__ hbuf, int* __restrict__ bar)
{
    const int U0 = blockIdx.x * 8;
    const int tid = threadIdx.x;
    const int b = tid & 31, uu = tid >> 5;
    const int unit = U0 + uu;
    const float4* __restrict__ wcol = Whd_t + unit;   // stride 512 float4 per k
    float c = c0t[unit * 32 + b];

    for (int t = 0; t < Tn; ++t) {
        const float* xr = Xd + ((size_t)(b * Tn + t)) * 2048 + unit;
        float zi = xr[0], zf = xr[512], zg = xr[1024], zo = xr[1536];
        if (t == 0) {
            const float* hsrc = h0t + b;   // written by enc kernel (flushed)
            #pragma unroll 8
            for (int k = 0; k < 512; ++k)
                fma4(hsrc[k * 32], wcol[(size_t)k * 512], zi, zf, zg, zo);
        } else {
            if (tid == 0) grid_wait(bar, 64 * t);
            __syncthreads();
            const float* hsrc = hbuf + ((t - 1) & 1) * 16384 + b;
            #pragma unroll 8
            for (int k = 0; k < 512; ++k) {
                const float hv = __hip_atomic_load(&hsrc[k * 32],
                                   __ATOMIC_RELAXED, __HIP_MEMORY_SCOPE_AGENT);
                fma4(hv, wcol[(size_t)k * 512], zi, zf, zg, zo);
            }
        }
        c = sigm(zf) * c + sigm(zi) * tanhf(zg);
        const float h = sigm(zo) * tanhf(c);
        h_all[((size_t)(b * Tn + t)) * Hn + unit] = h;
        if (t == Tn - 1) {
            hT[b * Hn + unit] = h;
            cT[b * Hn + unit] = c;
        } else {
            __hip_atomic_store(&hbuf[(t & 1) * 16384 + unit * 32 + b], h,
                               __ATOMIC_RELEASE, __HIP_MEMORY_SCOPE_AGENT);
            __syncthreads();
            if (tid == 0)
                __hip_atomic_fetch_add(bar, 1, __ATOMIC_ACQ_REL, __HIP_MEMORY_SCOPE_AGENT);
        }
    }
}

// ---------------------------------------------------------------------------
// Post-recurrence decoder step (unchanged)
// ---------------------------------------------------------------------------
__global__ __launch_bounds__(256) void dec_post_kernel(
    const float* __restrict__ h_all, const float* __restrict__ enc_proj,
    const float* __restrict__ z_proj, const float* __restrict__ enc_out,
    const float* __restrict__ x_seq, const float* __restrict__ Wo,
    const float* __restrict__ Wl, const float* __restrict__ bl,
    const int* __restrict__ value, const float* __restrict__ target_emb,
    float* __restrict__ outs, float* __restrict__ gattn,
    float* __restrict__ lamv, float* __restrict__ attn_pred)
{
    const int bt = blockIdx.x, b = bt >> 5;
    const int tid = threadIdx.x;
    __shared__ float h_sh[Hn];
    __shared__ float sc[2 * Sn];
    __shared__ float g_sh[Sn];
    __shared__ float ctx_sh[Hn];
    __shared__ float red[256];
    __shared__ int smax_sh;

    for (int i = tid; i < Hn; i += 256) h_sh[i] = h_all[(size_t)bt * Hn + i];
    __syncthreads();

    const int wave = tid >> 6, lane = tid & 63;
    for (int s = wave; s < Sn; s += 4) {
        const float* ep = enc_proj + ((size_t)b * Sn + s) * Hn;
        const float* zp = z_proj  + ((size_t)b * Sn + s) * Hn;
        float da = 0.f, db = 0.f;
        for (int j = lane; j < Hn; j += 64) {
            float hv = h_sh[j];
            da = fmaf(ep[j], hv, da);
            db = fmaf(zp[j], hv, db);
        }
        #pragma unroll
        for (int off = 32; off; off >>= 1) {
            da += __shfl_down(da, off);
            db += __shfl_down(db, off);
        }
        if (lane == 0) { sc[s] = da; sc[Sn + s] = db; }
    }
    __syncthreads();

    if (tid == 0) {
        float ma = -1e30f, mb = -1e30f;
        for (int s = 0; s < Sn; ++s) { ma = fmaxf(ma, sc[s]); mb = fmaxf(mb, sc[Sn + s]); }
        float sa = 0.f, sb = 0.f;
        for (int s = 0; s < Sn; ++s) {
            float ea = expf(sc[s] - ma), eb = expf(sc[Sn + s] - mb);
            sc[s] = ea; sc[Sn + s] = eb; sa += ea; sb += eb;
        }
        float gs = 0.f;
        for (int s = 0; s < Sn; ++s) { float g = (sc[s] / sa) * (sc[Sn + s] / sb); g_sh[s] = g; gs += g; }
        float inv = 1.f / (gs + 1e-9f);
        float best = -1.f; int bi = 0;
        for (int s = 0; s < Sn; ++s) {
            float g = g_sh[s] * inv; g_sh[s] = g;
            if (g > best) { best = g; bi = s; }
        }
        smax_sh = bi;
    }
    __syncthreads();

    for (int s = tid; s < Sn; s += 256) gattn[(size_t)bt * Sn + s] = g_sh[s];
    const int word = value[b * Sn + smax_sh];
    for (int e = tid; e < TEn; e += 256)
        attn_pred[(size_t)bt * TEn + e] = target_emb[(size_t)word * TEn + e];

    for (int u = tid; u < Hn; u += 256) {
        float acc = 0.f;
        for (int s = 0; s < Sn; ++s)
            acc = fmaf(g_sh[s], enc_out[((size_t)b * Sn + s) * Hn + u], acc);
        ctx_sh[u] = acc;
    }
    __syncthreads();

    for (int j = tid; j < Hn; j += 256) {
        float acc = 0.f;
        for (int k = 0; k < Hn; ++k) acc = fmaf(h_sh[k], Wo[(size_t)k * Hn + j], acc);
        for (int k = 0; k < Hn; ++k) acc = fmaf(ctx_sh[k], Wo[(size_t)(Hn + k) * Hn + j], acc);
        outs[(size_t)bt * Hn + j] = tanhf(acc);
    }

    float part = 0.f;
    for (int k = tid; k < Hn; k += 256) part = fmaf(h_sh[k], Wl[k], part);
    for (int k = tid; k < Hn; k += 256) part = fmaf(ctx_sh[k], Wl[Hn + k], part);
    const float* xr = x_seq + (size_t)bt * SEn;
    for (int k = tid; k < SEn; k += 256) part = fmaf(xr[k], Wl[2 * Hn + k], part);
    red[tid] = part;
    __syncthreads();
    for (int s2 = 128; s2; s2 >>= 1) {
        if (tid < s2) red[tid] += red[tid + s2];
        __syncthreads();
    }
    if (tid == 0) lamv[bt] = 1.f / (1.f + expf(-(red[0] + bl[0])));
}

// ---------------------------------------------------------------------------
// p_lex (unchanged)
// ---------------------------------------------------------------------------
__global__ __launch_bounds__(256) void p_lex_kernel(
    const float* __restrict__ gattn, const float* __restrict__ align_prob,
    float* __restrict__ p_lex)
{
    const int b = blockIdx.z, th = blockIdx.y, vc = blockIdx.x;
    const int tid = threadIdx.x;
    __shared__ float gT[Sn][17];
    for (int i = tid; i < Sn * 16; i += 256) {
        int s = i >> 4, tt = i & 15;
        gT[s][tt] = gattn[((size_t)(b * Tn + th * 16 + tt)) * Sn + s];
    }
    __syncthreads();
    const int v0 = vc * 1024 + tid * 4;
    if (v0 >= Vn) return;
    float acc[16][4] = {};
    for (int s = 0; s < Sn; ++s) {
        const float4 a = *(const float4*)(align_prob + ((size_t)b * Sn + s) * Vn + v0);
        #pragma unroll
        for (int tt = 0; tt < 16; ++tt) {
            float g = gT[s][tt];
            acc[tt][0] = fmaf(g, a.x, acc[tt][0]);
            acc[tt][1] = fmaf(g, a.y, acc[tt][1]);
            acc[tt][2] = fmaf(g, a.z, acc[tt][2]);
            acc[tt][3] = fmaf(g, a.w, acc[tt][3]);
        }
    }
    #pragma unroll
    for (int tt = 0; tt < 16; ++tt) {
        float4 o;
        o.x = acc[tt][0]; o.y = acc[tt][1]; o.z = acc[tt][2]; o.w = acc[tt][3];
        *(float4*)(p_lex + ((size_t)(b * Tn + th * 16 + tt)) * Vn + v0) = o;
    }
}

// ---------------------------------------------------------------------------
// Row reductions (unchanged)
// ---------------------------------------------------------------------------
__global__ __launch_bounds__(256) void reduce1_kernel(
    const float* __restrict__ z, float* __restrict__ lse1)
{
    const int r = blockIdx.x, tid = threadIdx.x;
    const float* row = z + (size_t)r * Vn;
    __shared__ float red[256];
    float m = -1e30f;
    for (int v = tid; v < Vn; v += 256) m = fmaxf(m, row[v]);
    red[tid] = m; __syncthreads();
    for (int s = 128; s; s >>= 1) { if (tid < s) red[tid] = fmaxf(red[tid], red[tid + s]); __syncthreads(); }
    m = red[0]; __syncthreads();
    float sum = 0.f;
    for (int v = tid; v < Vn; v += 256) sum += expf(row[v] - m);
    red[tid] = sum; __syncthreads();
    for (int s = 128; s; s >>= 1) { if (tid < s) red[tid] += red[tid + s]; __syncthreads(); }
    if (tid == 0) lse1[r] = m + logf(red[0]);
}

__global__ __launch_bounds__(256) void combine_kernel(
    float* __restrict__ q, const float* __restrict__ p_lex,
    const float* __restrict__ lamv, const float* __restrict__ lse1,
    float* __restrict__ lse2, int* __restrict__ amax)
{
    const int r = blockIdx.x, tid = threadIdx.x;
    const float l = lamv[r], ls1 = lse1[r];
    float* row = q + (size_t)r * Vn;
    const float* pl = p_lex + (size_t)r * Vn;
    __shared__ float rm[256];
    __shared__ int ri[256];
    float m = -1e30f; int mi = 0;
    for (int v = tid; v < Vn; v += 256) {
        float qq = l * pl[v] + (1.f - l) * (row[v] - ls1);
        row[v] = qq;
        if (qq > m) { m = qq; mi = v; }
    }
    rm[tid] = m; ri[tid] = mi; __syncthreads();
    for (int s = 128; s; s >>= 1) {
        if (tid < s) {
            if (rm[tid + s] > rm[tid] || (rm[tid + s] == rm[tid] && ri[tid + s] < ri[tid])) {
                rm[tid] = rm[tid + s]; ri[tid] = ri[tid + s];
            }
        }
        __syncthreads();
    }
    m = rm[0];
    const int best = ri[0];
    __syncthreads();
    float sum = 0.f;
    for (int v = tid; v < Vn; v += 256) sum += expf(row[v] - m);
    rm[tid] = sum; __syncthreads();
    for (int s = 128; s; s >>= 1) { if (tid < s) rm[tid] += rm[tid + s]; __syncthreads(); }
    if (tid == 0) { lse2[r] = m + logf(rm[0]); amax[r] = best; }
}

__global__ __launch_bounds__(256) void finalize_kernel(
    float* __restrict__ pbias, const float* __restrict__ lse2,
    const int* __restrict__ amax, const float* __restrict__ target_emb,
    float* __restrict__ dec_pred)
{
    const int r = blockIdx.x, tid = threadIdx.x;
    const float ls = lse2[r];
    float* row = pbias + (size_t)r * Vn;
    for (int v = tid; v < Vn; v += 256) row[v] -= ls;
    const int wd = amax[r];
    for (int e = tid; e < TEn; e += 256)
        dec_pred[(size_t)r * TEn + e] = target_emb[(size_t)wd * TEn + e];
}

// ---------------------------------------------------------------------------
extern "C" void kernel_launch(void* const* d_in, const int* in_sizes, int n_in,
                              void* d_out, int out_size, void* d_ws, size_t ws_size,
                              hipStream_t stream)
{
    const int*   sent       = (const int*)d_in[0];
    const int*   value      = (const int*)d_in[1];
    const int*   field      = (const int*)d_in[2];
    const int*   ppos       = (const int*)d_in[3];
    const int*   pneg       = (const int*)d_in[4];
    const float* align_prob = (const float*)d_in[7];
    const float* sent_emb   = (const float*)d_in[8];
    const float* field_emb  = (const float*)d_in[9];
    const float* ppos_emb   = (const float*)d_in[10];
    const float* pneg_emb   = (const float*)d_in[11];
    const float* target_emb = (const float*)d_in[12];
    const float* Wi_f = (const float*)d_in[13];
    const float* Wh_f = (const float*)d_in[14];
    const float* b_f  = (const float*)d_in[15];
    const float* Wi_b = (const float*)d_in[16];
    const float* Wh_b = (const float*)d_in[17];
    const float* b_b  = (const float*)d_in[18];
    const float* Wi_d = (const float*)d_in[19];
    const float* Wh_d = (const float*)d_in[20];
    const float* b_d  = (const float*)d_in[21];
    const float* Wa   = (const float*)d_in[22];
    const float* Wf   = (const float*)d_in[23];
    const float* Wo   = (const float*)d_in[24];
    const float* Wl   = (const float*)d_in[25];
    const float* bl   = (const float*)d_in[26];
    const float* Wout = (const float*)d_in[27];
    const float* bout = (const float*)d_in[28];

    // Workspace layout (floats)
    float* w = (float*)d_ws;
    float* enc_in   = w; w += (size_t)Bn * Sn * EINn;   // 1,472,000
    float* x_seq    = w; w += (size_t)Bn * Tn * SEn;    //   409,600
    float* Xf       = w; w += (size_t)Bn * Sn * 1024;   // 3,276,800
    float* Xb       = w; w += (size_t)Bn * Sn * 1024;   // 3,276,800
    float* Xd       = w; w += (size_t)Bn * Tn * 2048;   // 2,097,152
    float* enc_out  = w; w += (size_t)Bn * Sn * Hn;     // 1,638,400
    float* enc_proj = w; w += (size_t)Bn * Sn * Hn;     // 1,638,400
    float* z_proj   = w; w += (size_t)Bn * Sn * Hn;     // 1,638,400
    float* h0t      = w; w += (size_t)Bn * Hn;          //    16,384 ([k][b])
    float* c0t      = w; w += (size_t)Bn * Hn;          //    16,384 ([k][b])
    float* h_all    = w; w += (size_t)Bn * Tn * Hn;     //   524,288
    float* outs     = w; w += (size_t)Bn * Tn * Hn;     //   524,288
    float* gattn    = w; w += (size_t)Bn * Tn * Sn;     //   102,400
    float* lamv     = w; w += (size_t)Bn * Tn;          //     1,024
    float* p_lex    = w; w += (size_t)Bn * Tn * Vn;     // 20,480,000
    float* lse1     = w; w += (size_t)Bn * Tn;
    float* lse2     = w; w += (size_t)Bn * Tn;
    int*   amax     = (int*)w;

    // Transposed LSTM weights + LSTM h-exchange buffers + barrier counters,
    // aliased into the p_lex region (all dead before p_lex_kernel writes).
    float* Whf_t  = p_lex;                      //   262,144 floats
    float* Whb_t  = p_lex + 262144;             //   262,144
    float* Whd_t  = p_lex + 524288;             // 1,048,576
    float* hbuf_d = p_lex + 1600000;            //    32,768  ([2][512*32], [k][b])
    float* hbuf_e = p_lex + 1700000;            //    32,768  ([dir][2][256*32], [k][b])
    int*   bar_e  = (int*)(p_lex + 1800000);
    int*   bar_d  = bar_e + 64;                 // separate cacheline

    float* outp      = (float*)d_out;
    float* pbias     = outp;                       // [B,T,V]
    float* hT        = outp + (size_t)20480000;    // [B,H]
    float* cT        = hT + Bn * Hn;               // [B,H]
    float* attn_pred = cT + Bn * Hn;               // [B,T,300]
    float* dec_pred  = attn_pred + (size_t)Bn * Tn * TEn;

    const float4* Whf_t4 = (const float4*)Whf_t;
    const float4* Whb_t4 = (const float4*)Whb_t;
    const float4* Whd_t4 = (const float4*)Whd_t;

    // 1. embeddings + weight transposes + barrier reset
    embed_kernel<<<7350, 256, 0, stream>>>(value, field, ppos, pneg, sent,
        sent_emb, field_emb, ppos_emb, pneg_emb, enc_in, x_seq);
    transpose_wh_kernel<<<1280, 256, 0, stream>>>(Wh_f, Wh_b, Wh_d, Whf_t, Whb_t, Whd_t);
    hipMemsetAsync(bar_e, 0, 512, stream);

    // 2. input-side GEMMs
    dim3 gXf(8, 25);
    gemm128_kernel<<<gXf, 256, 0, stream>>>(enc_in, Wi_f, b_f, Xf, 3200, 1024, 460, 460, 1024, 1024);
    gemm128_kernel<<<gXf, 256, 0, stream>>>(enc_in, Wi_b, b_b, Xb, 3200, 1024, 460, 460, 1024, 1024);
    dim3 gXd(16, 8);
    gemm128_kernel<<<gXd, 256, 0, stream>>>(x_seq, Wi_d, b_d, Xd, 1024, 2048, 400, 400, 2048, 2048);

    // 3. encoder bidirectional LSTM — cooperative, batch-reuse
    {
        void* args[] = { (void*)&Xf, (void*)&Xb, (void*)&Whf_t4, (void*)&Whb_t4,
                         (void*)&enc_out, (void*)&h0t, (void*)&c0t,
                         (void*)&hbuf_e, (void*)&bar_e };
        hipLaunchCooperativeKernel((const void*)enc_lstm4_kernel,
                                   dim3(64), dim3(256), args, 0, stream);
    }

    // 4. attention key projections
    dim3 gPr(4, 25);
    gemm128_kernel<<<gPr, 256, 0, stream>>>(enc_out, Wa, nullptr, enc_proj, 3200, 512, 512, 512, 512, 512);
    gemm128_kernel<<<gPr, 256, 0, stream>>>(enc_in + 400, Wf, nullptr, z_proj, 3200, 512, 60, 460, 512, 512);

    // 5. decoder LSTM — cooperative, batch-reuse
    {
        void* args[] = { (void*)&Xd, (void*)&Whd_t4, (void*)&h0t, (void*)&c0t,
                         (void*)&h_all, (void*)&hT, (void*)&cT,
                         (void*)&hbuf_d, (void*)&bar_d };
        hipLaunchCooperativeKernel((const void*)dec_lstm4_kernel,
                                   dim3(64), dim3(256), args, 0, stream);
    }

    // 6. per-(b,t) attention/ctx/out/lam
    dec_post_kernel<<<1024, 256, 0, stream>>>(h_all, enc_proj, z_proj, enc_out, x_seq,
        Wo, Wl, bl, value, target_emb, outs, gattn, lamv, attn_pred);

    // 7. zmod = outs @ Wout + bout
    dim3 gBig(157, 8);
    gemm128_kernel<<<gBig, 256, 0, stream>>>(outs, Wout, bout, pbias, 1024, 20000, 512, 512, 20000, 20000);

    // 8. p_lex = attn @ align_prob
    dim3 gPl(20, 2, 32);
    p_lex_kernel<<<gPl, 256, 0, stream>>>(gattn, align_prob, p_lex);

    // 9-11. double log_softmax + argmax + gathers
    reduce1_kernel<<<1024, 256, 0, stream>>>(pbias, lse1);
    combine_kernel<<<1024, 256, 0, stream>>>(pbias, p_lex, lamv, lse1, lse2, amax);
    finalize_kernel<<<1024, 256, 0, stream>>>(pbias, lse2, amax, target_emb, dec_pred);

    (void)in_sizes; (void)n_in; (void)out_size; (void)ws_size;
}

// Round 4
// 4345.718 us; speedup vs baseline: 1.2644x; 1.2644x over previous
//
#include <hip/hip_runtime.h>
#include <cstdint>
#include <cstddef>

// Problem constants
static constexpr int Bn  = 32;     // batch
static constexpr int Tn  = 32;     // decoder steps
static constexpr int Sn  = 100;    // encoder length
static constexpr int Vn  = 20000;  // vocab
static constexpr int SEn = 400;    // word emb
static constexpr int EINn= 460;    // SE + FR
static constexpr int Hn  = 512;    // decoder hidden
static constexpr int HHn = 256;    // per-direction encoder hidden
static constexpr int TEn = 300;    // target emb

__device__ __forceinline__ float sigm(float x) { return 1.f / (1.f + expf(-x)); }

__device__ __forceinline__ void fma4(float hk, const float4 w,
                                     float& zi, float& zf, float& zg, float& zo) {
    zi = fmaf(hk, w.x, zi); zf = fmaf(hk, w.y, zf);
    zg = fmaf(hk, w.z, zg); zo = fmaf(hk, w.w, zo);
}

__device__ __forceinline__ void grid_wait(int* bar, int target) {
    while (__hip_atomic_load(bar, __ATOMIC_ACQUIRE, __HIP_MEMORY_SCOPE_AGENT) < target)
        __builtin_amdgcn_s_sleep(2);
}

// ---------------------------------------------------------------------------
// Embedding gathers
// ---------------------------------------------------------------------------
__global__ __launch_bounds__(256) void embed_kernel(
    const int* __restrict__ value, const int* __restrict__ field,
    const int* __restrict__ ppos, const int* __restrict__ pneg,
    const int* __restrict__ sent,
    const float* __restrict__ sent_emb, const float* __restrict__ field_emb,
    const float* __restrict__ ppos_emb, const float* __restrict__ pneg_emb,
    float* __restrict__ enc_in, float* __restrict__ x_seq)
{
    int i = blockIdx.x * 256 + threadIdx.x;
    const int total1 = Bn * Sn * EINn;
    if (i < total1) {
        int e = i % EINn, bs = i / EINn;
        float v;
        if (e < SEn)      v = sent_emb[(size_t)value[bs] * SEn + e];
        else if (e < 450) v = field_emb[field[bs] * 50 + (e - 400)];
        else if (e < 455) v = ppos_emb[ppos[bs] * 5 + (e - 450)];
        else              v = pneg_emb[pneg[bs] * 5 + (e - 455)];
        enc_in[i] = v;
    } else {
        int i2 = i - total1;
        if (i2 < Bn * Tn * SEn) {
            int e = i2 % SEn, bt = i2 / SEn;
            x_seq[i2] = sent_emb[(size_t)sent[bt] * SEn + e];
        }
    }
}

// ---------------------------------------------------------------------------
// Weight transposes into [k][u][gate] float4 layout for the LSTM kernels.
// enc: Wh[k][g*256+u] -> Wt[(k*256+u)*4+g], k,u in [0,256)
// dec: Wh[k][g*512+u] -> Wt[(k*512+u)*4+g], k,u in [0,512)
// ---------------------------------------------------------------------------
__global__ __launch_bounds__(256) void transpose_wh_kernel(
    const float* __restrict__ Whf, const float* __restrict__ Whb,
    const float* __restrict__ Whd,
    float* __restrict__ Whf_t, float* __restrict__ Whb_t, float* __restrict__ Whd_t)
{
    int i = blockIdx.x * 256 + threadIdx.x;
    if (i < 65536) {  // 256*256
        int k = i >> 8, u = i & 255;
        const float* p = Whf + (size_t)k * 1024 + u;
        float4 o;
        o.x = p[0]; o.y = p[256]; o.z = p[512]; o.w = p[768];
        *(float4*)(Whf_t + (size_t)i * 4) = o;
        p = Whb + (size_t)k * 1024 + u;
        o.x = p[0]; o.y = p[256]; o.z = p[512]; o.w = p[768];
        *(float4*)(Whb_t + (size_t)i * 4) = o;
    } else {
        int j = i - 65536;  // 512*512 entries
        if (j < 262144) {
            int k = j >> 9, u = j & 511;
            const float* p = Whd + (size_t)k * 2048 + u;
            float4 o;
            o.x = p[0]; o.y = p[512]; o.z = p[1024]; o.w = p[1536];
            *(float4*)(Whd_t + (size_t)j * 4) = o;
        }
    }
}

// ---------------------------------------------------------------------------
// Generic fp32 tiled GEMM (unchanged)
// ---------------------------------------------------------------------------
__global__ __launch_bounds__(256) void gemm128_kernel(
    const float* __restrict__ A, const float* __restrict__ Bm,
    const float* __restrict__ bias, float* __restrict__ C,
    int M, int N, int K, int lda, int ldb, int ldc)
{
    __shared__ float As[8][128];
    __shared__ float Bs[8][128];
    const int bm = blockIdx.y * 128, bn = blockIdx.x * 128;
    const int tid = threadIdx.x;
    const int tx = tid & 15, ty = tid >> 4;
    const int row0 = ty * 8, col0 = tx * 8;
    float acc[8][8] = {};
    for (int k0 = 0; k0 < K; k0 += 8) {
        #pragma unroll
        for (int i = 0; i < 4; ++i) {
            int idx = tid + 256 * i;
            int m = idx >> 3, kk = idx & 7;
            float v = 0.f;
            if (bm + m < M && k0 + kk < K) v = A[(size_t)(bm + m) * lda + (k0 + kk)];
            As[kk][m] = v;
        }
        #pragma unroll
        for (int i = 0; i < 4; ++i) {
            int idx = tid + 256 * i;
            int kk = idx >> 7, n = idx & 127;
            float v = 0.f;
            if (k0 + kk < K && bn + n < N) v = Bm[(size_t)(k0 + kk) * ldb + (bn + n)];
            Bs[kk][n] = v;
        }
        __syncthreads();
        #pragma unroll
        for (int kk = 0; kk < 8; ++kk) {
            float a[8], b[8];
            #pragma unroll
            for (int i = 0; i < 8; ++i) a[i] = As[kk][row0 + i];
            #pragma unroll
            for (int j = 0; j < 8; ++j) b[j] = Bs[kk][col0 + j];
            #pragma unroll
            for (int i = 0; i < 8; ++i)
                #pragma unroll
                for (int j = 0; j < 8; ++j) acc[i][j] = fmaf(a[i], b[j], acc[i][j]);
        }
        __syncthreads();
    }
    #pragma unroll
    for (int i = 0; i < 8; ++i) {
        int m = bm + row0 + i;
        if (m >= M) continue;
        #pragma unroll
        for (int j = 0; j < 8; ++j) {
            int n = bn + col0 + j;
            if (n < N) {
                float v = acc[i][j];
                if (bias) v += bias[n];
                C[(size_t)m * ldc + n] = v;
            }
        }
    }
}

// ---------------------------------------------------------------------------
// Encoder bidir LSTM v5 — batch-reuse + LDS h-staging, bit-exact chains.
// 64 blocks: block bb -> dir = bb>>5, units [(bb&31)*8, +8) of that dir.
// Thread: b = tid&31, uu = tid>>5 -> unit = U0+uu; full K=256 sequential
// fmaf chain, x-first, k-ascending (round-0 op order -> bit-identical).
// Per step: tid0 acquire-spin on counter (invalidates L1/L2), syncthreads,
// then PLAIN coalesced float4 loads stage all h into LDS [k][b] (32 KB);
// k-loop reads LDS (broadcast, conflict-free) + L1-resident weight float4s.
// Producer side: plain stores + syncthreads + tid0 ACQ_REL add (flushes L2).
// ---------------------------------------------------------------------------
__global__ __launch_bounds__(256, 1) void enc_lstm5_kernel(
    const float* __restrict__ Xf, const float* __restrict__ Xb,
    const float4* __restrict__ Whf_t, const float4* __restrict__ Whb_t,
    float* __restrict__ enc_out, float* __restrict__ h0t, float* __restrict__ c0t,
    float* __restrict__ hbuf, int* __restrict__ bar)
{
    const int bb  = blockIdx.x;
    const int dir = bb >> 5;
    const int U0  = (bb & 31) * 8;
    const float*  __restrict__ X = dir ? Xb : Xf;
    const float4* __restrict__ W = dir ? Whb_t : Whf_t;
    float* hb = hbuf + dir * 16384;          // per dir: [2][256*32], [k][b] layout
    const int tid = threadIdx.x;
    const int b = tid & 31, uu = tid >> 5;
    const int unit = U0 + uu;
    const float4* __restrict__ wcol = W + unit;   // stride 256 float4 per k
    __shared__ float h_lds[HHn * 32];             // [k][b], 32 KB
    float c = 0.f;

    for (int s = 0; s < Sn; ++s) {
        const int src_s = dir ? (Sn - 1 - s) : s;
        const float* xr = X + ((size_t)(b * Sn + src_s)) * 1024 + unit;
        float zi = xr[0], zf = xr[256], zg = xr[512], zo = xr[768];
        if (s > 0) {
            if (tid == 0) grid_wait(bar, 64 * s);
            __syncthreads();
            const float4* src4 = (const float4*)(hb + ((s - 1) & 1) * 8192);
            float4* dst4 = (float4*)h_lds;
            #pragma unroll
            for (int i = 0; i < 8; ++i)
                dst4[tid + i * 256] = src4[tid + i * 256];
            __syncthreads();
            #pragma unroll 8
            for (int k = 0; k < 256; ++k)
                fma4(h_lds[k * 32 + b], wcol[(size_t)k * 256], zi, zf, zg, zo);
        }
        c = sigm(zf) * c + sigm(zi) * tanhf(zg);
        const float h = sigm(zo) * tanhf(c);
        enc_out[((size_t)(b * Sn + src_s)) * Hn + dir * HHn + unit] = h;
        if (s == Sn - 1) {
            h0t[(dir * HHn + unit) * 32 + b] = h;   // [k][b] transposed
            c0t[(dir * HHn + unit) * 32 + b] = c;
        } else {
            hb[(s & 1) * 8192 + unit * 32 + b] = h;   // plain store (released by add)
            __syncthreads();
            if (tid == 0)
                __hip_atomic_fetch_add(bar, 1, __ATOMIC_ACQ_REL, __HIP_MEMORY_SCOPE_AGENT);
        }
    }
}

// ---------------------------------------------------------------------------
// Decoder LSTM v5 — batch-reuse + LDS h-staging, bit-exact chains.
// 64 blocks: block bb owns units [bb*8, +8) for ALL 32 batches.
// Thread: b = tid&31, uu = tid>>5 -> unit = U0+uu; full K=512 sequential
// fmaf chain, x-first, k-ascending (round-0 op order, bit-identical).
// h staged into LDS [k][b] (64 KB) via plain coalesced float4 loads per step.
// ---------------------------------------------------------------------------
__global__ __launch_bounds__(256, 1) void dec_lstm5_kernel(
    const float* __restrict__ Xd, const float4* __restrict__ Whd_t,
    const float* __restrict__ h0t, const float* __restrict__ c0t,
    float* __restrict__ h_all, float* __restrict__ hT, float* __restrict__ cT,
    float* __restrict__ hbuf, int* __restrict__ bar)
{
    const int U0 = blockIdx.x * 8;
    const int tid = threadIdx.x;
    const int b = tid & 31, uu = tid >> 5;
    const int unit = U0 + uu;
    const float4* __restrict__ wcol = Whd_t + unit;   // stride 512 float4 per k
    __shared__ float h_lds[Hn * 32];                  // [k][b], 64 KB
    float c = c0t[unit * 32 + b];

    for (int t = 0; t < Tn; ++t) {
        const float* xr = Xd + ((size_t)(b * Tn + t)) * 2048 + unit;
        float zi = xr[0], zf = xr[512], zg = xr[1024], zo = xr[1536];
        if (t > 0) {
            if (tid == 0) grid_wait(bar, 64 * t);
        }
        __syncthreads();
        const float4* src4 = (t == 0) ? (const float4*)h0t
                                      : (const float4*)(hbuf + ((t - 1) & 1) * 16384);
        float4* dst4 = (float4*)h_lds;
        #pragma unroll
        for (int i = 0; i < 16; ++i)
            dst4[tid + i * 256] = src4[tid + i * 256];
        __syncthreads();
        #pragma unroll 8
        for (int k = 0; k < 512; ++k)
            fma4(h_lds[k * 32 + b], wcol[(size_t)k * 512], zi, zf, zg, zo);
        c = sigm(zf) * c + sigm(zi) * tanhf(zg);
        const float h = sigm(zo) * tanhf(c);
        h_all[((size_t)(b * Tn + t)) * Hn + unit] = h;
        if (t == Tn - 1) {
            hT[b * Hn + unit] = h;
            cT[b * Hn + unit] = c;
        } else {
            hbuf[(t & 1) * 16384 + unit * 32 + b] = h;  // plain store (released by add)
            __syncthreads();
            if (tid == 0)
                __hip_atomic_fetch_add(bar, 1, __ATOMIC_ACQ_REL, __HIP_MEMORY_SCOPE_AGENT);
        }
    }
}

// ---------------------------------------------------------------------------
// Post-recurrence decoder step (unchanged)
// ---------------------------------------------------------------------------
__global__ __launch_bounds__(256) void dec_post_kernel(
    const float* __restrict__ h_all, const float* __restrict__ enc_proj,
    const float* __restrict__ z_proj, const float* __restrict__ enc_out,
    const float* __restrict__ x_seq, const float* __restrict__ Wo,
    const float* __restrict__ Wl, const float* __restrict__ bl,
    const int* __restrict__ value, const float* __restrict__ target_emb,
    float* __restrict__ outs, float* __restrict__ gattn,
    float* __restrict__ lamv, float* __restrict__ attn_pred)
{
    const int bt = blockIdx.x, b = bt >> 5;
    const int tid = threadIdx.x;
    __shared__ float h_sh[Hn];
    __shared__ float sc[2 * Sn];
    __shared__ float g_sh[Sn];
    __shared__ float ctx_sh[Hn];
    __shared__ float red[256];
    __shared__ int smax_sh;

    for (int i = tid; i < Hn; i += 256) h_sh[i] = h_all[(size_t)bt * Hn + i];
    __syncthreads();

    const int wave = tid >> 6, lane = tid & 63;
    for (int s = wave; s < Sn; s += 4) {
        const float* ep = enc_proj + ((size_t)b * Sn + s) * Hn;
        const float* zp = z_proj  + ((size_t)b * Sn + s) * Hn;
        float da = 0.f, db = 0.f;
        for (int j = lane; j < Hn; j += 64) {
            float hv = h_sh[j];
            da = fmaf(ep[j], hv, da);
            db = fmaf(zp[j], hv, db);
        }
        #pragma unroll
        for (int off = 32; off; off >>= 1) {
            da += __shfl_down(da, off);
            db += __shfl_down(db, off);
        }
        if (lane == 0) { sc[s] = da; sc[Sn + s] = db; }
    }
    __syncthreads();

    if (tid == 0) {
        float ma = -1e30f, mb = -1e30f;
        for (int s = 0; s < Sn; ++s) { ma = fmaxf(ma, sc[s]); mb = fmaxf(mb, sc[Sn + s]); }
        float sa = 0.f, sb = 0.f;
        for (int s = 0; s < Sn; ++s) {
            float ea = expf(sc[s] - ma), eb = expf(sc[Sn + s] - mb);
            sc[s] = ea; sc[Sn + s] = eb; sa += ea; sb += eb;
        }
        float gs = 0.f;
        for (int s = 0; s < Sn; ++s) { float g = (sc[s] / sa) * (sc[Sn + s] / sb); g_sh[s] = g; gs += g; }
        float inv = 1.f / (gs + 1e-9f);
        float best = -1.f; int bi = 0;
        for (int s = 0; s < Sn; ++s) {
            float g = g_sh[s] * inv; g_sh[s] = g;
            if (g > best) { best = g; bi = s; }
        }
        smax_sh = bi;
    }
    __syncthreads();

    for (int s = tid; s < Sn; s += 256) gattn[(size_t)bt * Sn + s] = g_sh[s];
    const int word = value[b * Sn + smax_sh];
    for (int e = tid; e < TEn; e += 256)
        attn_pred[(size_t)bt * TEn + e] = target_emb[(size_t)word * TEn + e];

    for (int u = tid; u < Hn; u += 256) {
        float acc = 0.f;
        for (int s = 0; s < Sn; ++s)
            acc = fmaf(g_sh[s], enc_out[((size_t)b * Sn + s) * Hn + u], acc);
        ctx_sh[u] = acc;
    }
    __syncthreads();

    for (int j = tid; j < Hn; j += 256) {
        float acc = 0.f;
        for (int k = 0; k < Hn; ++k) acc = fmaf(h_sh[k], Wo[(size_t)k * Hn + j], acc);
        for (int k = 0; k < Hn; ++k) acc = fmaf(ctx_sh[k], Wo[(size_t)(Hn + k) * Hn + j], acc);
        outs[(size_t)bt * Hn + j] = tanhf(acc);
    }

    float part = 0.f;
    for (int k = tid; k < Hn; k += 256) part = fmaf(h_sh[k], Wl[k], part);
    for (int k = tid; k < Hn; k += 256) part = fmaf(ctx_sh[k], Wl[Hn + k], part);
    const float* xr = x_seq + (size_t)bt * SEn;
    for (int k = tid; k < SEn; k += 256) part = fmaf(xr[k], Wl[2 * Hn + k], part);
    red[tid] = part;
    __syncthreads();
    for (int s2 = 128; s2; s2 >>= 1) {
        if (tid < s2) red[tid] += red[tid + s2];
        __syncthreads();
    }
    if (tid == 0) lamv[bt] = 1.f / (1.f + expf(-(red[0] + bl[0])));
}

// ---------------------------------------------------------------------------
// p_lex (unchanged)
// ---------------------------------------------------------------------------
__global__ __launch_bounds__(256) void p_lex_kernel(
    const float* __restrict__ gattn, const float* __restrict__ align_prob,
    float* __restrict__ p_lex)
{
    const int b = blockIdx.z, th = blockIdx.y, vc = blockIdx.x;
    const int tid = threadIdx.x;
    __shared__ float gT[Sn][17];
    for (int i = tid; i < Sn * 16; i += 256) {
        int s = i >> 4, tt = i & 15;
        gT[s][tt] = gattn[((size_t)(b * Tn + th * 16 + tt)) * Sn + s];
    }
    __syncthreads();
    const int v0 = vc * 1024 + tid * 4;
    if (v0 >= Vn) return;
    float acc[16][4] = {};
    for (int s = 0; s < Sn; ++s) {
        const float4 a = *(const float4*)(align_prob + ((size_t)b * Sn + s) * Vn + v0);
        #pragma unroll
        for (int tt = 0; tt < 16; ++tt) {
            float g = gT[s][tt];
            acc[tt][0] = fmaf(g, a.x, acc[tt][0]);
            acc[tt][1] = fmaf(g, a.y, acc[tt][1]);
            acc[tt][2] = fmaf(g, a.z, acc[tt][2]);
            acc[tt][3] = fmaf(g, a.w, acc[tt][3]);
        }
    }
    #pragma unroll
    for (int tt = 0; tt < 16; ++tt) {
        float4 o;
        o.x = acc[tt][0]; o.y = acc[tt][1]; o.z = acc[tt][2]; o.w = acc[tt][3];
        *(float4*)(p_lex + ((size_t)(b * Tn + th * 16 + tt)) * Vn + v0) = o;
    }
}

// ---------------------------------------------------------------------------
// Row reductions (unchanged)
// ---------------------------------------------------------------------------
__global__ __launch_bounds__(256) void reduce1_kernel(
    const float* __restrict__ z, float* __restrict__ lse1)
{
    const int r = blockIdx.x, tid = threadIdx.x;
    const float* row = z + (size_t)r * Vn;
    __shared__ float red[256];
    float m = -1e30f;
    for (int v = tid; v < Vn; v += 256) m = fmaxf(m, row[v]);
    red[tid] = m; __syncthreads();
    for (int s = 128; s; s >>= 1) { if (tid < s) red[tid] = fmaxf(red[tid], red[tid + s]); __syncthreads(); }
    m = red[0]; __syncthreads();
    float sum = 0.f;
    for (int v = tid; v < Vn; v += 256) sum += expf(row[v] - m);
    red[tid] = sum; __syncthreads();
    for (int s = 128; s; s >>= 1) { if (tid < s) red[tid] += red[tid + s]; __syncthreads(); }
    if (tid == 0) lse1[r] = m + logf(red[0]);
}

__global__ __launch_bounds__(256) void combine_kernel(
    float* __restrict__ q, const float* __restrict__ p_lex,
    const float* __restrict__ lamv, const float* __restrict__ lse1,
    float* __restrict__ lse2, int* __restrict__ amax)
{
    const int r = blockIdx.x, tid = threadIdx.x;
    const float l = lamv[r], ls1 = lse1[r];
    float* row = q + (size_t)r * Vn;
    const float* pl = p_lex + (size_t)r * Vn;
    __shared__ float rm[256];
    __shared__ int ri[256];
    float m = -1e30f; int mi = 0;
    for (int v = tid; v < Vn; v += 256) {
        float qq = l * pl[v] + (1.f - l) * (row[v] - ls1);
        row[v] = qq;
        if (qq > m) { m = qq; mi = v; }
    }
    rm[tid] = m; ri[tid] = mi; __syncthreads();
    for (int s = 128; s; s >>= 1) {
        if (tid < s) {
            if (rm[tid + s] > rm[tid] || (rm[tid + s] == rm[tid] && ri[tid + s] < ri[tid])) {
                rm[tid] = rm[tid + s]; ri[tid] = ri[tid + s];
            }
        }
        __syncthreads();
    }
    m = rm[0];
    const int best = ri[0];
    __syncthreads();
    float sum = 0.f;
    for (int v = tid; v < Vn; v += 256) sum += expf(row[v] - m);
    rm[tid] = sum; __syncthreads();
    for (int s = 128; s; s >>= 1) { if (tid < s) rm[tid] += rm[tid + s]; __syncthreads(); }
    if (tid == 0) { lse2[r] = m + logf(rm[0]); amax[r] = best; }
}

__global__ __launch_bounds__(256) void finalize_kernel(
    float* __restrict__ pbias, const float* __restrict__ lse2,
    const int* __restrict__ amax, const float* __restrict__ target_emb,
    float* __restrict__ dec_pred)
{
    const int r = blockIdx.x, tid = threadIdx.x;
    const float ls = lse2[r];
    float* row = pbias + (size_t)r * Vn;
    for (int v = tid; v < Vn; v += 256) row[v] -= ls;
    const int wd = amax[r];
    for (int e = tid; e < TEn; e += 256)
        dec_pred[(size_t)r * TEn + e] = target_emb[(size_t)wd * TEn + e];
}

// ---------------------------------------------------------------------------
extern "C" void kernel_launch(void* const* d_in, const int* in_sizes, int n_in,
                              void* d_out, int out_size, void* d_ws, size_t ws_size,
                              hipStream_t stream)
{
    const int*   sent       = (const int*)d_in[0];
    const int*   value      = (const int*)d_in[1];
    const int*   field      = (const int*)d_in[2];
    const int*   ppos       = (const int*)d_in[3];
    const int*   pneg       = (const int*)d_in[4];
    const float* align_prob = (const float*)d_in[7];
    const float* sent_emb   = (const float*)d_in[8];
    const float* field_emb  = (const float*)d_in[9];
    const float* ppos_emb   = (const float*)d_in[10];
    const float* pneg_emb   = (const float*)d_in[11];
    const float* target_emb = (const float*)d_in[12];
    const float* Wi_f = (const float*)d_in[13];
    const float* Wh_f = (const float*)d_in[14];
    const float* b_f  = (const float*)d_in[15];
    const float* Wi_b = (const float*)d_in[16];
    const float* Wh_b = (const float*)d_in[17];
    const float* b_b  = (const float*)d_in[18];
    const float* Wi_d = (const float*)d_in[19];
    const float* Wh_d = (const float*)d_in[20];
    const float* b_d  = (const float*)d_in[21];
    const float* Wa   = (const float*)d_in[22];
    const float* Wf   = (const float*)d_in[23];
    const float* Wo   = (const float*)d_in[24];
    const float* Wl   = (const float*)d_in[25];
    const float* bl   = (const float*)d_in[26];
    const float* Wout = (const float*)d_in[27];
    const float* bout = (const float*)d_in[28];

    // Workspace layout (floats)
    float* w = (float*)d_ws;
    float* enc_in   = w; w += (size_t)Bn * Sn * EINn;   // 1,472,000
    float* x_seq    = w; w += (size_t)Bn * Tn * SEn;    //   409,600
    float* Xf       = w; w += (size_t)Bn * Sn * 1024;   // 3,276,800
    float* Xb       = w; w += (size_t)Bn * Sn * 1024;   // 3,276,800
    float* Xd       = w; w += (size_t)Bn * Tn * 2048;   // 2,097,152
    float* enc_out  = w; w += (size_t)Bn * Sn * Hn;     // 1,638,400
    float* enc_proj = w; w += (size_t)Bn * Sn * Hn;     // 1,638,400
    float* z_proj   = w; w += (size_t)Bn * Sn * Hn;     // 1,638,400
    float* h0t      = w; w += (size_t)Bn * Hn;          //    16,384 ([k][b])
    float* c0t      = w; w += (size_t)Bn * Hn;          //    16,384 ([k][b])
    float* h_all    = w; w += (size_t)Bn * Tn * Hn;     //   524,288
    float* outs     = w; w += (size_t)Bn * Tn * Hn;     //   524,288
    float* gattn    = w; w += (size_t)Bn * Tn * Sn;     //   102,400
    float* lamv     = w; w += (size_t)Bn * Tn;          //     1,024
    float* p_lex    = w; w += (size_t)Bn * Tn * Vn;     // 20,480,000
    float* lse1     = w; w += (size_t)Bn * Tn;
    float* lse2     = w; w += (size_t)Bn * Tn;
    int*   amax     = (int*)w;

    // Transposed LSTM weights + LSTM h-exchange buffers + barrier counters,
    // aliased into the p_lex region (all dead before p_lex_kernel writes).
    float* Whf_t  = p_lex;                      //   262,144 floats
    float* Whb_t  = p_lex + 262144;             //   262,144
    float* Whd_t  = p_lex + 524288;             // 1,048,576
    float* hbuf_d = p_lex + 1600000;            //    32,768  ([2][512*32], [k][b])
    float* hbuf_e = p_lex + 1700000;            //    32,768  ([dir][2][256*32], [k][b])
    int*   bar_e  = (int*)(p_lex + 1800000);
    int*   bar_d  = bar_e + 64;                 // separate cacheline

    float* outp      = (float*)d_out;
    float* pbias     = outp;                       // [B,T,V]
    float* hT        = outp + (size_t)20480000;    // [B,H]
    float* cT        = hT + Bn * Hn;               // [B,H]
    float* attn_pred = cT + Bn * Hn;               // [B,T,300]
    float* dec_pred  = attn_pred + (size_t)Bn * Tn * TEn;

    const float4* Whf_t4 = (const float4*)Whf_t;
    const float4* Whb_t4 = (const float4*)Whb_t;
    const float4* Whd_t4 = (const float4*)Whd_t;

    // 1. embeddings + weight transposes + barrier reset
    embed_kernel<<<7350, 256, 0, stream>>>(value, field, ppos, pneg, sent,
        sent_emb, field_emb, ppos_emb, pneg_emb, enc_in, x_seq);
    transpose_wh_kernel<<<1280, 256, 0, stream>>>(Wh_f, Wh_b, Wh_d, Whf_t, Whb_t, Whd_t);
    hipMemsetAsync(bar_e, 0, 512, stream);

    // 2. input-side GEMMs
    dim3 gXf(8, 25);
    gemm128_kernel<<<gXf, 256, 0, stream>>>(enc_in, Wi_f, b_f, Xf, 3200, 1024, 460, 460, 1024, 1024);
    gemm128_kernel<<<gXf, 256, 0, stream>>>(enc_in, Wi_b, b_b, Xb, 3200, 1024, 460, 460, 1024, 1024);
    dim3 gXd(16, 8);
    gemm128_kernel<<<gXd, 256, 0, stream>>>(x_seq, Wi_d, b_d, Xd, 1024, 2048, 400, 400, 2048, 2048);

    // 3. encoder bidirectional LSTM — cooperative, batch-reuse + LDS staging
    {
        void* args[] = { (void*)&Xf, (void*)&Xb, (void*)&Whf_t4, (void*)&Whb_t4,
                         (void*)&enc_out, (void*)&h0t, (void*)&c0t,
                         (void*)&hbuf_e, (void*)&bar_e };
        hipLaunchCooperativeKernel((const void*)enc_lstm5_kernel,
                                   dim3(64), dim3(256), args, 0, stream);
    }

    // 4. attention key projections
    dim3 gPr(4, 25);
    gemm128_kernel<<<gPr, 256, 0, stream>>>(enc_out, Wa, nullptr, enc_proj, 3200, 512, 512, 512, 512, 512);
    gemm128_kernel<<<gPr, 256, 0, stream>>>(enc_in + 400, Wf, nullptr, z_proj, 3200, 512, 60, 460, 512, 512);

    // 5. decoder LSTM — cooperative, batch-reuse + LDS staging
    {
        void* args[] = { (void*)&Xd, (void*)&Whd_t4, (void*)&h0t, (void*)&c0t,
                         (void*)&h_all, (void*)&hT, (void*)&cT,
                         (void*)&hbuf_d, (void*)&bar_d };
        hipLaunchCooperativeKernel((const void*)dec_lstm5_kernel,
                                   dim3(64), dim3(256), args, 0, stream);
    }

    // 6. per-(b,t) attention/ctx/out/lam
    dec_post_kernel<<<1024, 256, 0, stream>>>(h_all, enc_proj, z_proj, enc_out, x_seq,
        Wo, Wl, bl, value, target_emb, outs, gattn, lamv, attn_pred);

    // 7. zmod = outs @ Wout + bout
    dim3 gBig(157, 8);
    gemm128_kernel<<<gBig, 256, 0, stream>>>(outs, Wout, bout, pbias, 1024, 20000, 512, 512, 20000, 20000);

    // 8. p_lex = attn @ align_prob
    dim3 gPl(20, 2, 32);
    p_lex_kernel<<<gPl, 256, 0, stream>>>(gattn, align_prob, p_lex);

    // 9-11. double log_softmax + argmax + gathers
    reduce1_kernel<<<1024, 256, 0, stream>>>(pbias, lse1);
    combine_kernel<<<1024, 256, 0, stream>>>(pbias, p_lex, lamv, lse1, lse2, amax);
    finalize_kernel<<<1024, 256, 0, stream>>>(pbias, lse2, amax, target_emb, dec_pred);

    (void)in_sizes; (void)n_in; (void)out_size; (void)ws_size;
}

// Round 5
// 4152.920 us; speedup vs baseline: 1.3231x; 1.0464x over previous
//
#include <hip/hip_runtime.h>
#include <cstdint>
#include <cstddef>

// Problem constants
static constexpr int Bn  = 32;     // batch
static constexpr int Tn  = 32;     // decoder steps
static constexpr int Sn  = 100;    // encoder length
static constexpr int Vn  = 20000;  // vocab
static constexpr int SEn = 400;    // word emb
static constexpr int EINn= 460;    // SE + FR
static constexpr int Hn  = 512;    // decoder hidden
static constexpr int HHn = 256;    // per-direction encoder hidden
static constexpr int TEn = 300;    // target emb

__device__ __forceinline__ float sigm(float x) { return 1.f / (1.f + expf(-x)); }

__device__ __forceinline__ void fma4(float hk, const float4 w,
                                     float& zi, float& zf, float& zg, float& zo) {
    zi = fmaf(hk, w.x, zi); zf = fmaf(hk, w.y, zf);
    zg = fmaf(hk, w.z, zg); zo = fmaf(hk, w.w, zo);
}

// ---------------------------------------------------------------------------
// Embedding gathers
// ---------------------------------------------------------------------------
__global__ __launch_bounds__(256) void embed_kernel(
    const int* __restrict__ value, const int* __restrict__ field,
    const int* __restrict__ ppos, const int* __restrict__ pneg,
    const int* __restrict__ sent,
    const float* __restrict__ sent_emb, const float* __restrict__ field_emb,
    const float* __restrict__ ppos_emb, const float* __restrict__ pneg_emb,
    float* __restrict__ enc_in, float* __restrict__ x_seq)
{
    int i = blockIdx.x * 256 + threadIdx.x;
    const int total1 = Bn * Sn * EINn;
    if (i < total1) {
        int e = i % EINn, bs = i / EINn;
        float v;
        if (e < SEn)      v = sent_emb[(size_t)value[bs] * SEn + e];
        else if (e < 450) v = field_emb[field[bs] * 50 + (e - 400)];
        else if (e < 455) v = ppos_emb[ppos[bs] * 5 + (e - 450)];
        else              v = pneg_emb[pneg[bs] * 5 + (e - 455)];
        enc_in[i] = v;
    } else {
        int i2 = i - total1;
        if (i2 < Bn * Tn * SEn) {
            int e = i2 % SEn, bt = i2 / SEn;
            x_seq[i2] = sent_emb[(size_t)sent[bt] * SEn + e];
        }
    }
}

// ---------------------------------------------------------------------------
// Weight transposes into [k][u][gate] float4 layout for the LSTM kernels.
// enc: Wh[k][g*256+u] -> Wt[(k*256+u)*4+g], k,u in [0,256)
// dec: Wh[k][g*512+u] -> Wt[(k*512+u)*4+g], k,u in [0,512)
// ---------------------------------------------------------------------------
__global__ __launch_bounds__(256) void transpose_wh_kernel(
    const float* __restrict__ Whf, const float* __restrict__ Whb,
    const float* __restrict__ Whd,
    float* __restrict__ Whf_t, float* __restrict__ Whb_t, float* __restrict__ Whd_t)
{
    int i = blockIdx.x * 256 + threadIdx.x;
    if (i < 65536) {  // 256*256
        int k = i >> 8, u = i & 255;
        const float* p = Whf + (size_t)k * 1024 + u;
        float4 o;
        o.x = p[0]; o.y = p[256]; o.z = p[512]; o.w = p[768];
        *(float4*)(Whf_t + (size_t)i * 4) = o;
        p = Whb + (size_t)k * 1024 + u;
        o.x = p[0]; o.y = p[256]; o.z = p[512]; o.w = p[768];
        *(float4*)(Whb_t + (size_t)i * 4) = o;
    } else {
        int j = i - 65536;  // 512*512 entries
        if (j < 262144) {
            int k = j >> 9, u = j & 511;
            const float* p = Whd + (size_t)k * 2048 + u;
            float4 o;
            o.x = p[0]; o.y = p[512]; o.z = p[1024]; o.w = p[1536];
            *(float4*)(Whd_t + (size_t)j * 4) = o;
        }
    }
}

// ---------------------------------------------------------------------------
// Generic fp32 tiled GEMM (unchanged)
// ---------------------------------------------------------------------------
__global__ __launch_bounds__(256) void gemm128_kernel(
    const float* __restrict__ A, const float* __restrict__ Bm,
    const float* __restrict__ bias, float* __restrict__ C,
    int M, int N, int K, int lda, int ldb, int ldc)
{
    __shared__ float As[8][128];
    __shared__ float Bs[8][128];
    const int bm = blockIdx.y * 128, bn = blockIdx.x * 128;
    const int tid = threadIdx.x;
    const int tx = tid & 15, ty = tid >> 4;
    const int row0 = ty * 8, col0 = tx * 8;
    float acc[8][8] = {};
    for (int k0 = 0; k0 < K; k0 += 8) {
        #pragma unroll
        for (int i = 0; i < 4; ++i) {
            int idx = tid + 256 * i;
            int m = idx >> 3, kk = idx & 7;
            float v = 0.f;
            if (bm + m < M && k0 + kk < K) v = A[(size_t)(bm + m) * lda + (k0 + kk)];
            As[kk][m] = v;
        }
        #pragma unroll
        for (int i = 0; i < 4; ++i) {
            int idx = tid + 256 * i;
            int kk = idx >> 7, n = idx & 127;
            float v = 0.f;
            if (k0 + kk < K && bn + n < N) v = Bm[(size_t)(k0 + kk) * ldb + (bn + n)];
            Bs[kk][n] = v;
        }
        __syncthreads();
        #pragma unroll
        for (int kk = 0; kk < 8; ++kk) {
            float a[8], b[8];
            #pragma unroll
            for (int i = 0; i < 8; ++i) a[i] = As[kk][row0 + i];
            #pragma unroll
            for (int j = 0; j < 8; ++j) b[j] = Bs[kk][col0 + j];
            #pragma unroll
            for (int i = 0; i < 8; ++i)
                #pragma unroll
                for (int j = 0; j < 8; ++j) acc[i][j] = fmaf(a[i], b[j], acc[i][j]);
        }
        __syncthreads();
    }
    #pragma unroll
    for (int i = 0; i < 8; ++i) {
        int m = bm + row0 + i;
        if (m >= M) continue;
        #pragma unroll
        for (int j = 0; j < 8; ++j) {
            int n = bn + col0 + j;
            if (n < N) {
                float v = acc[i][j];
                if (bias) v += bias[n];
                C[(size_t)m * ldc + n] = v;
            }
        }
    }
}

// ---------------------------------------------------------------------------
// Encoder bidir LSTM — round-0 proven design (block = (batch,dir), h in LDS,
// no cross-block traffic, no barriers, weights stream from L2).
// Only change vs round 0: final h/c additionally written in [k][b]-transposed
// layout (h0t/c0t) for the cooperative decoder. Bit-exact fmaf chain.
// ---------------------------------------------------------------------------
__global__ __launch_bounds__(256) void enc_lstm2_kernel(
    const float* __restrict__ Xf, const float* __restrict__ Xb,
    const float4* __restrict__ Whf_t, const float4* __restrict__ Whb_t,
    float* __restrict__ enc_out, float* __restrict__ h0t, float* __restrict__ c0t)
{
    const int b = blockIdx.x >> 1, dir = blockIdx.x & 1;
    const float* __restrict__ X = dir ? Xb : Xf;
    const float4* __restrict__ W = dir ? Whb_t : Whf_t;
    __shared__ __align__(16) float h_sh[HHn];
    const int u = threadIdx.x;
    float c = 0.f;
    h_sh[u] = 0.f;
    __syncthreads();
    for (int step = 0; step < Sn; ++step) {
        const int s = dir ? (Sn - 1 - step) : step;
        const float* xr = X + ((size_t)(b * Sn + s)) * 1024;
        float zi = xr[u], zf = xr[256 + u], zg = xr[512 + u], zo = xr[768 + u];
        #pragma unroll 4
        for (int k4 = 0; k4 < 64; ++k4) {
            const float4 hv = *(const float4*)&h_sh[k4 << 2];
            const float4 w0 = W[((k4 << 2) + 0) * 256 + u];
            const float4 w1 = W[((k4 << 2) + 1) * 256 + u];
            const float4 w2 = W[((k4 << 2) + 2) * 256 + u];
            const float4 w3 = W[((k4 << 2) + 3) * 256 + u];
            fma4(hv.x, w0, zi, zf, zg, zo);
            fma4(hv.y, w1, zi, zf, zg, zo);
            fma4(hv.z, w2, zi, zf, zg, zo);
            fma4(hv.w, w3, zi, zf, zg, zo);
        }
        c = sigm(zf) * c + sigm(zi) * tanhf(zg);
        float h = sigm(zo) * tanhf(c);
        __syncthreads();
        h_sh[u] = h;
        enc_out[((size_t)(b * Sn + s)) * Hn + dir * HHn + u] = h;
        if (step == Sn - 1) {
            h0t[(dir * HHn + u) * 32 + b] = h;   // [k][b] transposed for decoder
            c0t[(dir * HHn + u) * 32 + b] = c;
        }
        __syncthreads();
    }
}

// ---------------------------------------------------------------------------
// Decoder LSTM v6 — batch-reuse cooperative, L2-preserving coherence.
// 64 blocks: block bb owns units [bb*8, +8) for ALL 32 batches.
// Thread: b = tid&31, uu = tid>>5 -> unit = U0+uu; full K=512 sequential
// fmaf chain, x-first, k-ascending (round-0 op order, bit-identical).
// Coherence protocol (no L2 invalidates => weights stay L2-resident):
//  producer: plain stores -> syncthreads -> tid0 fetch_add(RELEASE)
//            (release = wb of dirty lines to IC; clean weight lines untouched)
//  consumer: tid0 RELAXED polls (no inv); h staged via relaxed AGENT-scope
//            8-byte atomic loads (global_load sc1 -> read IC directly).
// ---------------------------------------------------------------------------
__global__ __launch_bounds__(256, 1) void dec_lstm6_kernel(
    const float* __restrict__ Xd, const float4* __restrict__ Whd_t,
    const float* __restrict__ h0t, const float* __restrict__ c0t,
    float* __restrict__ h_all, float* __restrict__ hT, float* __restrict__ cT,
    float* __restrict__ hbuf, int* __restrict__ bar)
{
    const int U0 = blockIdx.x * 8;
    const int tid = threadIdx.x;
    const int b = tid & 31, uu = tid >> 5;
    const int unit = U0 + uu;
    const float4* __restrict__ wcol = Whd_t + unit;   // stride 512 float4 per k
    __shared__ float h_lds[Hn * 32];                  // [k][b], 64 KB
    float c = c0t[unit * 32 + b];

    for (int t = 0; t < Tn; ++t) {
        const float* xr = Xd + ((size_t)(b * Tn + t)) * 2048 + unit;
        float zi = xr[0], zf = xr[512], zg = xr[1024], zo = xr[1536];
        if (t == 0) {
            // h0t written by previous kernel (flushed at kernel boundary)
            const float4* src4 = (const float4*)h0t;
            float4* dst4 = (float4*)h_lds;
            #pragma unroll
            for (int i = 0; i < 16; ++i)
                dst4[tid + i * 256] = src4[tid + i * 256];
        } else {
            if (tid == 0) {
                while (__hip_atomic_load(bar, __ATOMIC_RELAXED,
                                         __HIP_MEMORY_SCOPE_AGENT) < 64 * t)
                    __builtin_amdgcn_s_sleep(2);
            }
            __syncthreads();
            const unsigned long long* src8 =
                (const unsigned long long*)(hbuf + ((t - 1) & 1) * 16384);
            unsigned long long* dst8 = (unsigned long long*)h_lds;
            #pragma unroll
            for (int i = 0; i < 32; ++i)
                dst8[tid + i * 256] = __hip_atomic_load(&src8[tid + i * 256],
                                        __ATOMIC_RELAXED, __HIP_MEMORY_SCOPE_AGENT);
        }
        __syncthreads();
        #pragma unroll 8
        for (int k = 0; k < 512; ++k)
            fma4(h_lds[k * 32 + b], wcol[(size_t)k * 512], zi, zf, zg, zo);
        c = sigm(zf) * c + sigm(zi) * tanhf(zg);
        const float h = sigm(zo) * tanhf(c);
        h_all[((size_t)(b * Tn + t)) * Hn + unit] = h;
        if (t == Tn - 1) {
            hT[b * Hn + unit] = h;
            cT[b * Hn + unit] = c;
        } else {
            hbuf[(t & 1) * 16384 + unit * 32 + b] = h;  // plain store
            __syncthreads();                             // all stores issued+drained
            if (tid == 0)
                __hip_atomic_fetch_add(bar, 1, __ATOMIC_RELEASE,
                                       __HIP_MEMORY_SCOPE_AGENT);
        }
    }
}

// ---------------------------------------------------------------------------
// Post-recurrence decoder step (unchanged)
// ---------------------------------------------------------------------------
__global__ __launch_bounds__(256) void dec_post_kernel(
    const float* __restrict__ h_all, const float* __restrict__ enc_proj,
    const float* __restrict__ z_proj, const float* __restrict__ enc_out,
    const float* __restrict__ x_seq, const float* __restrict__ Wo,
    const float* __restrict__ Wl, const float* __restrict__ bl,
    const int* __restrict__ value, const float* __restrict__ target_emb,
    float* __restrict__ outs, float* __restrict__ gattn,
    float* __restrict__ lamv, float* __restrict__ attn_pred)
{
    const int bt = blockIdx.x, b = bt >> 5;
    const int tid = threadIdx.x;
    __shared__ float h_sh[Hn];
    __shared__ float sc[2 * Sn];
    __shared__ float g_sh[Sn];
    __shared__ float ctx_sh[Hn];
    __shared__ float red[256];
    __shared__ int smax_sh;

    for (int i = tid; i < Hn; i += 256) h_sh[i] = h_all[(size_t)bt * Hn + i];
    __syncthreads();

    const int wave = tid >> 6, lane = tid & 63;
    for (int s = wave; s < Sn; s += 4) {
        const float* ep = enc_proj + ((size_t)b * Sn + s) * Hn;
        const float* zp = z_proj  + ((size_t)b * Sn + s) * Hn;
        float da = 0.f, db = 0.f;
        for (int j = lane; j < Hn; j += 64) {
            float hv = h_sh[j];
            da = fmaf(ep[j], hv, da);
            db = fmaf(zp[j], hv, db);
        }
        #pragma unroll
        for (int off = 32; off; off >>= 1) {
            da += __shfl_down(da, off);
            db += __shfl_down(db, off);
        }
        if (lane == 0) { sc[s] = da; sc[Sn + s] = db; }
    }
    __syncthreads();

    if (tid == 0) {
        float ma = -1e30f, mb = -1e30f;
        for (int s = 0; s < Sn; ++s) { ma = fmaxf(ma, sc[s]); mb = fmaxf(mb, sc[Sn + s]); }
        float sa = 0.f, sb = 0.f;
        for (int s = 0; s < Sn; ++s) {
            float ea = expf(sc[s] - ma), eb = expf(sc[Sn + s] - mb);
            sc[s] = ea; sc[Sn + s] = eb; sa += ea; sb += eb;
        }
        float gs = 0.f;
        for (int s = 0; s < Sn; ++s) { float g = (sc[s] / sa) * (sc[Sn + s] / sb); g_sh[s] = g; gs += g; }
        float inv = 1.f / (gs + 1e-9f);
        float best = -1.f; int bi = 0;
        for (int s = 0; s < Sn; ++s) {
            float g = g_sh[s] * inv; g_sh[s] = g;
            if (g > best) { best = g; bi = s; }
        }
        smax_sh = bi;
    }
    __syncthreads();

    for (int s = tid; s < Sn; s += 256) gattn[(size_t)bt * Sn + s] = g_sh[s];
    const int word = value[b * Sn + smax_sh];
    for (int e = tid; e < TEn; e += 256)
        attn_pred[(size_t)bt * TEn + e] = target_emb[(size_t)word * TEn + e];

    for (int u = tid; u < Hn; u += 256) {
        float acc = 0.f;
        for (int s = 0; s < Sn; ++s)
            acc = fmaf(g_sh[s], enc_out[((size_t)b * Sn + s) * Hn + u], acc);
        ctx_sh[u] = acc;
    }
    __syncthreads();

    for (int j = tid; j < Hn; j += 256) {
        float acc = 0.f;
        for (int k = 0; k < Hn; ++k) acc = fmaf(h_sh[k], Wo[(size_t)k * Hn + j], acc);
        for (int k = 0; k < Hn; ++k) acc = fmaf(ctx_sh[k], Wo[(size_t)(Hn + k) * Hn + j], acc);
        outs[(size_t)bt * Hn + j] = tanhf(acc);
    }

    float part = 0.f;
    for (int k = tid; k < Hn; k += 256) part = fmaf(h_sh[k], Wl[k], part);
    for (int k = tid; k < Hn; k += 256) part = fmaf(ctx_sh[k], Wl[Hn + k], part);
    const float* xr = x_seq + (size_t)bt * SEn;
    for (int k = tid; k < SEn; k += 256) part = fmaf(xr[k], Wl[2 * Hn + k], part);
    red[tid] = part;
    __syncthreads();
    for (int s2 = 128; s2; s2 >>= 1) {
        if (tid < s2) red[tid] += red[tid + s2];
        __syncthreads();
    }
    if (tid == 0) lamv[bt] = 1.f / (1.f + expf(-(red[0] + bl[0])));
}

// ---------------------------------------------------------------------------
// p_lex (unchanged)
// ---------------------------------------------------------------------------
__global__ __launch_bounds__(256) void p_lex_kernel(
    const float* __restrict__ gattn, const float* __restrict__ align_prob,
    float* __restrict__ p_lex)
{
    const int b = blockIdx.z, th = blockIdx.y, vc = blockIdx.x;
    const int tid = threadIdx.x;
    __shared__ float gT[Sn][17];
    for (int i = tid; i < Sn * 16; i += 256) {
        int s = i >> 4, tt = i & 15;
        gT[s][tt] = gattn[((size_t)(b * Tn + th * 16 + tt)) * Sn + s];
    }
    __syncthreads();
    const int v0 = vc * 1024 + tid * 4;
    if (v0 >= Vn) return;
    float acc[16][4] = {};
    for (int s = 0; s < Sn; ++s) {
        const float4 a = *(const float4*)(align_prob + ((size_t)b * Sn + s) * Vn + v0);
        #pragma unroll
        for (int tt = 0; tt < 16; ++tt) {
            float g = gT[s][tt];
            acc[tt][0] = fmaf(g, a.x, acc[tt][0]);
            acc[tt][1] = fmaf(g, a.y, acc[tt][1]);
            acc[tt][2] = fmaf(g, a.z, acc[tt][2]);
            acc[tt][3] = fmaf(g, a.w, acc[tt][3]);
        }
    }
    #pragma unroll
    for (int tt = 0; tt < 16; ++tt) {
        float4 o;
        o.x = acc[tt][0]; o.y = acc[tt][1]; o.z = acc[tt][2]; o.w = acc[tt][3];
        *(float4*)(p_lex + ((size_t)(b * Tn + th * 16 + tt)) * Vn + v0) = o;
    }
}

// ---------------------------------------------------------------------------
// Row reductions (unchanged)
// ---------------------------------------------------------------------------
__global__ __launch_bounds__(256) void reduce1_kernel(
    const float* __restrict__ z, float* __restrict__ lse1)
{
    const int r = blockIdx.x, tid = threadIdx.x;
    const float* row = z + (size_t)r * Vn;
    __shared__ float red[256];
    float m = -1e30f;
    for (int v = tid; v < Vn; v += 256) m = fmaxf(m, row[v]);
    red[tid] = m; __syncthreads();
    for (int s = 128; s; s >>= 1) { if (tid < s) red[tid] = fmaxf(red[tid], red[tid + s]); __syncthreads(); }
    m = red[0]; __syncthreads();
    float sum = 0.f;
    for (int v = tid; v < Vn; v += 256) sum += expf(row[v] - m);
    red[tid] = sum; __syncthreads();
    for (int s = 128; s; s >>= 1) { if (tid < s) red[tid] += red[tid + s]; __syncthreads(); }
    if (tid == 0) lse1[r] = m + logf(red[0]);
}

__global__ __launch_bounds__(256) void combine_kernel(
    float* __restrict__ q, const float* __restrict__ p_lex,
    const float* __restrict__ lamv, const float* __restrict__ lse1,
    float* __restrict__ lse2, int* __restrict__ amax)
{
    const int r = blockIdx.x, tid = threadIdx.x;
    const float l = lamv[r], ls1 = lse1[r];
    float* row = q + (size_t)r * Vn;
    const float* pl = p_lex + (size_t)r * Vn;
    __shared__ float rm[256];
    __shared__ int ri[256];
    float m = -1e30f; int mi = 0;
    for (int v = tid; v < Vn; v += 256) {
        float qq = l * pl[v] + (1.f - l) * (row[v] - ls1);
        row[v] = qq;
        if (qq > m) { m = qq; mi = v; }
    }
    rm[tid] = m; ri[tid] = mi; __syncthreads();
    for (int s = 128; s; s >>= 1) {
        if (tid < s) {
            if (rm[tid + s] > rm[tid] || (rm[tid + s] == rm[tid] && ri[tid + s] < ri[tid])) {
                rm[tid] = rm[tid + s]; ri[tid] = ri[tid + s];
            }
        }
        __syncthreads();
    }
    m = rm[0];
    const int best = ri[0];
    __syncthreads();
    float sum = 0.f;
    for (int v = tid; v < Vn; v += 256) sum += expf(row[v] - m);
    rm[tid] = sum; __syncthreads();
    for (int s = 128; s; s >>= 1) { if (tid < s) rm[tid] += rm[tid + s]; __syncthreads(); }
    if (tid == 0) { lse2[r] = m + logf(rm[0]); amax[r] = best; }
}

__global__ __launch_bounds__(256) void finalize_kernel(
    float* __restrict__ pbias, const float* __restrict__ lse2,
    const int* __restrict__ amax, const float* __restrict__ target_emb,
    float* __restrict__ dec_pred)
{
    const int r = blockIdx.x, tid = threadIdx.x;
    const float ls = lse2[r];
    float* row = pbias + (size_t)r * Vn;
    for (int v = tid; v < Vn; v += 256) row[v] -= ls;
    const int wd = amax[r];
    for (int e = tid; e < TEn; e += 256)
        dec_pred[(size_t)r * TEn + e] = target_emb[(size_t)wd * TEn + e];
}

// ---------------------------------------------------------------------------
extern "C" void kernel_launch(void* const* d_in, const int* in_sizes, int n_in,
                              void* d_out, int out_size, void* d_ws, size_t ws_size,
                              hipStream_t stream)
{
    const int*   sent       = (const int*)d_in[0];
    const int*   value      = (const int*)d_in[1];
    const int*   field      = (const int*)d_in[2];
    const int*   ppos       = (const int*)d_in[3];
    const int*   pneg       = (const int*)d_in[4];
    const float* align_prob = (const float*)d_in[7];
    const float* sent_emb   = (const float*)d_in[8];
    const float* field_emb  = (const float*)d_in[9];
    const float* ppos_emb   = (const float*)d_in[10];
    const float* pneg_emb   = (const float*)d_in[11];
    const float* target_emb = (const float*)d_in[12];
    const float* Wi_f = (const float*)d_in[13];
    const float* Wh_f = (const float*)d_in[14];
    const float* b_f  = (const float*)d_in[15];
    const float* Wi_b = (const float*)d_in[16];
    const float* Wh_b = (const float*)d_in[17];
    const float* b_b  = (const float*)d_in[18];
    const float* Wi_d = (const float*)d_in[19];
    const float* Wh_d = (const float*)d_in[20];
    const float* b_d  = (const float*)d_in[21];
    const float* Wa   = (const float*)d_in[22];
    const float* Wf   = (const float*)d_in[23];
    const float* Wo   = (const float*)d_in[24];
    const float* Wl   = (const float*)d_in[25];
    const float* bl   = (const float*)d_in[26];
    const float* Wout = (const float*)d_in[27];
    const float* bout = (const float*)d_in[28];

    // Workspace layout (floats)
    float* w = (float*)d_ws;
    float* enc_in   = w; w += (size_t)Bn * Sn * EINn;   // 1,472,000
    float* x_seq    = w; w += (size_t)Bn * Tn * SEn;    //   409,600
    float* Xf       = w; w += (size_t)Bn * Sn * 1024;   // 3,276,800
    float* Xb       = w; w += (size_t)Bn * Sn * 1024;   // 3,276,800
    float* Xd       = w; w += (size_t)Bn * Tn * 2048;   // 2,097,152
    float* enc_out  = w; w += (size_t)Bn * Sn * Hn;     // 1,638,400
    float* enc_proj = w; w += (size_t)Bn * Sn * Hn;     // 1,638,400
    float* z_proj   = w; w += (size_t)Bn * Sn * Hn;     // 1,638,400
    float* h0t      = w; w += (size_t)Bn * Hn;          //    16,384 ([k][b])
    float* c0t      = w; w += (size_t)Bn * Hn;          //    16,384 ([k][b])
    float* h_all    = w; w += (size_t)Bn * Tn * Hn;     //   524,288
    float* outs     = w; w += (size_t)Bn * Tn * Hn;     //   524,288
    float* gattn    = w; w += (size_t)Bn * Tn * Sn;     //   102,400
    float* lamv     = w; w += (size_t)Bn * Tn;          //     1,024
    float* p_lex    = w; w += (size_t)Bn * Tn * Vn;     // 20,480,000
    float* lse1     = w; w += (size_t)Bn * Tn;
    float* lse2     = w; w += (size_t)Bn * Tn;
    int*   amax     = (int*)w;

    // Transposed LSTM weights + decoder h-exchange buffer + barrier counter,
    // aliased into the p_lex region (all dead before p_lex_kernel writes).
    float* Whf_t  = p_lex;                      //   262,144 floats
    float* Whb_t  = p_lex + 262144;             //   262,144
    float* Whd_t  = p_lex + 524288;             // 1,048,576
    float* hbuf_d = p_lex + 1600000;            //    32,768  ([2][512*32], [k][b])
    int*   bar_d  = (int*)(p_lex + 1800000);

    float* outp      = (float*)d_out;
    float* pbias     = outp;                       // [B,T,V]
    float* hT        = outp + (size_t)20480000;    // [B,H]
    float* cT        = hT + Bn * Hn;               // [B,H]
    float* attn_pred = cT + Bn * Hn;               // [B,T,300]
    float* dec_pred  = attn_pred + (size_t)Bn * Tn * TEn;

    const float4* Whf_t4 = (const float4*)Whf_t;
    const float4* Whb_t4 = (const float4*)Whb_t;
    const float4* Whd_t4 = (const float4*)Whd_t;

    // 1. embeddings + weight transposes + barrier reset
    embed_kernel<<<7350, 256, 0, stream>>>(value, field, ppos, pneg, sent,
        sent_emb, field_emb, ppos_emb, pneg_emb, enc_in, x_seq);
    transpose_wh_kernel<<<1280, 256, 0, stream>>>(Wh_f, Wh_b, Wh_d, Whf_t, Whb_t, Whd_t);
    hipMemsetAsync(bar_d, 0, 256, stream);

    // 2. input-side GEMMs
    dim3 gXf(8, 25);
    gemm128_kernel<<<gXf, 256, 0, stream>>>(enc_in, Wi_f, b_f, Xf, 3200, 1024, 460, 460, 1024, 1024);
    gemm128_kernel<<<gXf, 256, 0, stream>>>(enc_in, Wi_b, b_b, Xb, 3200, 1024, 460, 460, 1024, 1024);
    dim3 gXd(16, 8);
    gemm128_kernel<<<gXd, 256, 0, stream>>>(x_seq, Wi_d, b_d, Xd, 1024, 2048, 400, 400, 2048, 2048);

    // 3. encoder bidirectional LSTM — round-0 design (h in LDS, no barriers)
    enc_lstm2_kernel<<<64, 256, 0, stream>>>(Xf, Xb, Whf_t4, Whb_t4,
        enc_out, h0t, c0t);

    // 4. attention key projections
    dim3 gPr(4, 25);
    gemm128_kernel<<<gPr, 256, 0, stream>>>(enc_out, Wa, nullptr, enc_proj, 3200, 512, 512, 512, 512, 512);
    gemm128_kernel<<<gPr, 256, 0, stream>>>(enc_in + 400, Wf, nullptr, z_proj, 3200, 512, 60, 460, 512, 512);

    // 5. decoder LSTM — cooperative, batch-reuse, L2-preserving coherence
    {
        void* args[] = { (void*)&Xd, (void*)&Whd_t4, (void*)&h0t, (void*)&c0t,
                         (void*)&h_all, (void*)&hT, (void*)&cT,
                         (void*)&hbuf_d, (void*)&bar_d };
        hipLaunchCooperativeKernel((const void*)dec_lstm6_kernel,
                                   dim3(64), dim3(256), args, 0, stream);
    }

    // 6. per-(b,t) attention/ctx/out/lam
    dec_post_kernel<<<1024, 256, 0, stream>>>(h_all, enc_proj, z_proj, enc_out, x_seq,
        Wo, Wl, bl, value, target_emb, outs, gattn, lamv, attn_pred);

    // 7. zmod = outs @ Wout + bout
    dim3 gBig(157, 8);
    gemm128_kernel<<<gBig, 256, 0, stream>>>(outs, Wout, bout, pbias, 1024, 20000, 512, 512, 20000, 20000);

    // 8. p_lex = attn @ align_prob
    dim3 gPl(20, 2, 32);
    p_lex_kernel<<<gPl, 256, 0, stream>>>(gattn, align_prob, p_lex);

    // 9-11. double log_softmax + argmax + gathers
    reduce1_kernel<<<1024, 256, 0, stream>>>(pbias, lse1);
    combine_kernel<<<1024, 256, 0, stream>>>(pbias, p_lex, lamv, lse1, lse2, amax);
    finalize_kernel<<<1024, 256, 0, stream>>>(pbias, lse2, amax, target_emb, dec_pred);

    (void)in_sizes; (void)n_in; (void)out_size; (void)ws_size;
}